// Round 3
// baseline (3779.568 us; speedup 1.0000x reference)
//
#include <hip/hip_runtime.h>
#include <math.h>

#define S_LEN 2048
#define B_SZ 8
#define D_IN 1024
#define DS_ 128
#define INV_TEMP (1.0f/1.000001f)
#define QROW 260    // Q2 row stride: qa(128) ka1(128) g(1) pad
#define LBUF 1092   // LDS floats per step slot: 5 sections*192 + v(128) + g + pad

// ---------------------------------------------------------------------------
// Kernel 1: fused projection GEMM  P[16384][512] = x @ [Wk|Wv|Wq|Wa]^T
// P row layout: k(0..127) v(128..255) q(256..383) r(384..511)
// ---------------------------------------------------------------------------
__global__ __launch_bounds__(256) void proj_gemm(
    const float* __restrict__ X,
    const float* __restrict__ Wk, const float* __restrict__ Wv,
    const float* __restrict__ Wq, const float* __restrict__ Wa,
    float* __restrict__ P)
{
    __shared__ __align__(16) float As[32][68];
    __shared__ __align__(16) float Bs[32][68];
    const int tid = threadIdx.x;
    const int m0 = blockIdx.x * 64;
    const int n0 = blockIdx.y * 64;
    const int lr = tid >> 3;
    const int lk4 = tid & 7;

    const float* wrows[2];
#pragma unroll
    for (int i = 0; i < 2; i++) {
        int nn = n0 + lr + i * 32;
        const float* w;
        if      (nn < 128) w = Wk + (size_t)nn * D_IN;
        else if (nn < 256) w = Wv + (size_t)(nn - 128) * D_IN;
        else if (nn < 384) w = Wq + (size_t)(nn - 256) * D_IN;
        else               w = Wa + (size_t)(nn - 384) * D_IN;
        wrows[i] = w;
    }
    const int ty = tid >> 4, tx = tid & 15;
    float acc[4][4];
#pragma unroll
    for (int i = 0; i < 4; i++)
#pragma unroll
        for (int j = 0; j < 4; j++) acc[i][j] = 0.f;

    for (int k0 = 0; k0 < D_IN; k0 += 32) {
#pragma unroll
        for (int i = 0; i < 2; i++) {
            int m = lr + i * 32;
            float4 a4 = *(const float4*)(X + (size_t)(m0 + m) * D_IN + k0 + lk4 * 4);
            As[lk4*4+0][m] = a4.x; As[lk4*4+1][m] = a4.y;
            As[lk4*4+2][m] = a4.z; As[lk4*4+3][m] = a4.w;
            float4 b4 = *(const float4*)(wrows[i] + k0 + lk4 * 4);
            Bs[lk4*4+0][m] = b4.x; Bs[lk4*4+1][m] = b4.y;
            Bs[lk4*4+2][m] = b4.z; Bs[lk4*4+3][m] = b4.w;
        }
        __syncthreads();
#pragma unroll
        for (int kk = 0; kk < 32; kk++) {
            float4 a4 = *(const float4*)(&As[kk][ty * 4]);
            float4 b4 = *(const float4*)(&Bs[kk][tx * 4]);
            float a[4] = {a4.x, a4.y, a4.z, a4.w};
            float b[4] = {b4.x, b4.y, b4.z, b4.w};
#pragma unroll
            for (int i = 0; i < 4; i++)
#pragma unroll
                for (int j = 0; j < 4; j++)
                    acc[i][j] = fmaf(a[i], b[j], acc[i][j]);
        }
        __syncthreads();
    }
#pragma unroll
    for (int i = 0; i < 4; i++) {
        float4 o; o.x = acc[i][0]; o.y = acc[i][1]; o.z = acc[i][2]; o.w = acc[i][3];
        *(float4*)(P + (size_t)(m0 + ty * 4 + i) * 512 + n0 + tx * 4) = o;
    }
}

// ---------------------------------------------------------------------------
// Kernel 2: postprocess per token. In-place on P: k<-l2norm(k), q<-l2norm(q),
// r-slot<-alpha. Side buffer Q2: qa=q*alpha, ka1=k*(1-alpha), g=sum q(1-a)k.
// ---------------------------------------------------------------------------
__global__ __launch_bounds__(128) void postproc(
    float* __restrict__ P, float* __restrict__ Q2,
    const float* __restrict__ bA, const float* __restrict__ lam)
{
    const int tok = blockIdx.x, i = threadIdx.x;
    float* row = P + (size_t)tok * 512;
    float kr = row[i], qr = row[256 + i], rr = row[384 + i];
    float ks = kr * kr, qs = qr * qr;
#pragma unroll
    for (int m = 1; m < 64; m <<= 1) { ks += __shfl_xor(ks, m); qs += __shfl_xor(qs, m); }
    __shared__ float sb[6];
    if ((i & 63) == 0) { sb[(i >> 6) * 2] = ks; sb[(i >> 6) * 2 + 1] = qs; }
    __syncthreads();
    float kinv = 1.0f / fmaxf(sqrtf(sb[0] + sb[2]), 1e-12f);
    float qinv = 1.0f / fmaxf(sqrtf(sb[1] + sb[3]), 1e-12f);
    float kn = kr * kinv, qn = qr * qinv;
    float sr = 1.0f / (1.0f + __expf(-(rr + bA[i])));
    float sl = 1.0f / (1.0f + __expf(-lam[i]));
    float la = logf(sl + 1e-8f);
    float al = __expf(8.0f * sr * la);
    row[i] = kn; row[256 + i] = qn; row[384 + i] = al;
    float* q2 = Q2 + (size_t)tok * QROW;
    q2[i] = qn * al;
    q2[128 + i] = kn * (1.0f - al);
    float gi = qn * (1.0f - al) * kn;
#pragma unroll
    for (int m = 1; m < 64; m <<= 1) gi += __shfl_xor(gi, m);
    if ((i & 63) == 0) sb[4 + (i >> 6)] = gi;
    __syncthreads();
    if (i == 0) q2[256] = sb[4] + sb[5];
}

// ---------------------------------------------------------------------------
// Kernel 3: sequential recurrence. 8 blocks x 512 threads.
// Thread (c=tid&15, vp=tid>>4) owns H[k][v], k in [c*8,c*8+8), v in [vp*4,vp*4+4).
// LDS step slot: sections k@0 q@192 qa@384 a@576 ka1@768 (16 chunks of 8,
// stride 12 -> 16B aligned b128, 2-way banks = free), v@960, g@1088.
// One barrier/step; 2-deep global prefetch; a/ka1 reads issued pre-barrier.
// ---------------------------------------------------------------------------
__global__ __launch_bounds__(512, 2) void recurrence(
    const float* __restrict__ P, const float* __restrict__ Q2, float* __restrict__ Y)
{
    const int b = blockIdx.x;
    const int tid = threadIdx.x;
    const int c = tid & 15;
    const int vp = tid >> 4;      // 0..31
    const int lane = tid & 63;
    const int wave = tid >> 6;    // 0..7
    const int co = c * 12;

    __shared__ __align__(16) float Pbuf[3][LBUF];
    __shared__ __align__(16) float errw[2][8];

    const float* Pb = P + (size_t)b * S_LEN * 512;
    const float* Qb = Q2 + (size_t)b * S_LEN * QROW;
    float* Yb = Y + (size_t)b * S_LEN * DS_;

    float4 H0={0,0,0,0},H1={0,0,0,0},H2={0,0,0,0},H3={0,0,0,0},
           H4={0,0,0,0},H5={0,0,0,0},H6={0,0,0,0},H7={0,0,0,0};

    const bool isS = tid < 385;
    int spos = 0; const float* src = nullptr; int sstr = 0;
    if (tid < 256) {
        int i = tid * 2, s = i >> 7, idx = i & 127, cp = (idx >> 3) * 12 + (idx & 7);
        spos = (s == 0) ? cp : (s == 1) ? (960 + idx) : (s == 2) ? (192 + cp) : (576 + cp);
        src = Pb + i; sstr = 512;
    } else if (tid < 385) {
        int i2 = (tid - 256) * 2, s = i2 >> 7, idx = i2 & 127, cp = (idx >> 3) * 12 + (idx & 7);
        spos = (tid == 384) ? 1088 : ((s == 0) ? (384 + cp) : (768 + cp));
        src = Qb + i2; sstr = QROW;
    }

    float2 r0 = {0.f, 0.f}, r1 = {0.f, 0.f};
    if (isS) { r0 = *(const float2*)(src); r1 = *(const float2*)(src + sstr); }
    if (isS) *(float2*)(&Pbuf[0][spos]) = r0;
    __syncthreads();

#define RED16(v4) { _Pragma("unroll") for (int m_ = 1; m_ < 16; m_ <<= 1) { \
    v4.x += __shfl_xor(v4.x, m_); v4.y += __shfl_xor(v4.y, m_); \
    v4.z += __shfl_xor(v4.z, m_); v4.w += __shfl_xor(v4.w, m_); } }

#define DOTJ(qs, ks, zs, Hj) { \
    pr.x = fmaf(qs, Hj.x, pr.x); pr.y = fmaf(qs, Hj.y, pr.y); \
    pr.z = fmaf(qs, Hj.z, pr.z); pr.w = fmaf(qs, Hj.w, pr.w); \
    kp.x = fmaf(ks, Hj.x, kp.x); kp.y = fmaf(ks, Hj.y, kp.y); \
    kp.z = fmaf(ks, Hj.z, kp.z); kp.w = fmaf(ks, Hj.w, kp.w); \
    ya.x = fmaf(zs, Hj.x, ya.x); ya.y = fmaf(zs, Hj.y, ya.y); \
    ya.z = fmaf(zs, Hj.z, ya.z); ya.w = fmaf(zs, Hj.w, ya.w); }

#define UPDJ(as_, ws_, Hj) { \
    Hj.x = fmaf(as_, Hj.x, ws_ * sd.x); Hj.y = fmaf(as_, Hj.y, ws_ * sd.y); \
    Hj.z = fmaf(as_, Hj.z, ws_ * sd.z); Hj.w = fmaf(as_, Hj.w, ws_ * sd.w); }

#define STEP(T, PAR, RS_, RL_) { \
    float* cb = &Pbuf[(T) % 3][0]; \
    const float4 k0 = *(const float4*)(cb + co); \
    const float4 k1 = *(const float4*)(cb + co + 4); \
    const float4 q0 = *(const float4*)(cb + 192 + co); \
    const float4 q1 = *(const float4*)(cb + 192 + co + 4); \
    const float4 z0 = *(const float4*)(cb + 384 + co); \
    const float4 z1 = *(const float4*)(cb + 384 + co + 4); \
    const float4 vt = *(const float4*)(cb + 960 + vp * 4); \
    const float g = cb[1088]; \
    float4 pr = {0,0,0,0}, kp = {0,0,0,0}, ya = {0,0,0,0}; \
    DOTJ(q0.x, k0.x, z0.x, H0) DOTJ(q0.y, k0.y, z0.y, H1) \
    DOTJ(q0.z, k0.z, z0.z, H2) DOTJ(q0.w, k0.w, z0.w, H3) \
    DOTJ(q1.x, k1.x, z1.x, H4) DOTJ(q1.y, k1.y, z1.y, H5) \
    DOTJ(q1.z, k1.z, z1.z, H6) DOTJ(q1.w, k1.w, z1.w, H7) \
    RED16(pr) RED16(kp) RED16(ya) \
    float4 d4; d4.x = vt.x - kp.x; d4.y = vt.y - kp.y; \
    d4.z = vt.z - kp.z; d4.w = vt.w - kp.w; \
    float ex = vt.x - pr.x, ey = vt.y - pr.y, ez = vt.z - pr.z, ew = vt.w - pr.w; \
    float ep = fmaf(ex, ex, fmaf(ey, ey, fmaf(ez, ez, ew * ew))); \
    ep += __shfl_xor(ep, 16); ep += __shfl_xor(ep, 32); \
    if (lane == 0) errw[PAR][wave] = ep; \
    if ((T) + 1 < S_LEN && isS) *(float2*)(&Pbuf[((T) + 1) % 3][spos]) = RS_; \
    if ((T) + 2 < S_LEN && isS) RL_ = *(const float2*)(src + (size_t)((T) + 2) * sstr); \
    const float4 a0 = *(const float4*)(cb + 576 + co); \
    const float4 a1 = *(const float4*)(cb + 576 + co + 4); \
    const float4 w0 = *(const float4*)(cb + 768 + co); \
    const float4 w1 = *(const float4*)(cb + 768 + co + 4); \
    __syncthreads(); \
    const float4 ea = *(const float4*)(&errw[PAR][0]); \
    const float4 eb = *(const float4*)(&errw[PAR][4]); \
    float err = ((ea.x + ea.y) + (ea.z + ea.w)) + ((eb.x + eb.y) + (eb.z + eb.w)); \
    float sur = 1.0f / (1.0f + __expf(-err * INV_TEMP)); \
    float4 sd; sd.x = sur * d4.x; sd.y = sur * d4.y; \
    sd.z = sur * d4.z; sd.w = sur * d4.w; \
    if (c == 0) { \
        float sg = sur * g; float4 y4; \
        y4.x = fmaf(sg, d4.x, ya.x); y4.y = fmaf(sg, d4.y, ya.y); \
        y4.z = fmaf(sg, d4.z, ya.z); y4.w = fmaf(sg, d4.w, ya.w); \
        *(float4*)(Yb + (size_t)(T) * DS_ + vp * 4) = y4; } \
    UPDJ(a0.x, w0.x, H0) UPDJ(a0.y, w0.y, H1) \
    UPDJ(a0.z, w0.z, H2) UPDJ(a0.w, w0.w, H3) \
    UPDJ(a1.x, w1.x, H4) UPDJ(a1.y, w1.y, H5) \
    UPDJ(a1.z, w1.z, H6) UPDJ(a1.w, w1.w, H7) \
}

    for (int t = 0; t < S_LEN; t += 2) {
        STEP(t,     0, r1, r0)
        STEP(t + 1, 1, r0, r1)
    }
#undef RED16
#undef DOTJ
#undef UPDJ
#undef STEP
}

// ---------------------------------------------------------------------------
// Kernel 4: RMSNorm over DS per token (in-place on Y)
// ---------------------------------------------------------------------------
__global__ __launch_bounds__(128) void rmsnorm(
    float* __restrict__ Y, const float* __restrict__ nw)
{
    const int tok = blockIdx.x, i = threadIdx.x;
    float y = Y[(size_t)tok * DS_ + i];
    float s = y * y;
#pragma unroll
    for (int m = 1; m < 64; m <<= 1) s += __shfl_xor(s, m);
    __shared__ float sb[2];
    if ((i & 63) == 0) sb[i >> 6] = s;
    __syncthreads();
    float ms = (sb[0] + sb[1]) * (1.0f / 128.0f);
    Y[(size_t)tok * DS_ + i] = y * rsqrtf(ms + 1e-6f) * nw[i];
}

// ---------------------------------------------------------------------------
// Kernel 5: output GEMM  Out[16384][1024] = Yn[16384][128] @ Wo[1024][128]^T
// ---------------------------------------------------------------------------
__global__ __launch_bounds__(256) void out_gemm(
    const float* __restrict__ Yn, const float* __restrict__ Wo, float* __restrict__ Out)
{
    __shared__ __align__(16) float As[32][68];
    __shared__ __align__(16) float Bs[32][68];
    const int tid = threadIdx.x;
    const int m0 = blockIdx.x * 64;
    const int n0 = blockIdx.y * 64;
    const int lr = tid >> 3;
    const int lk4 = tid & 7;
    const int ty = tid >> 4, tx = tid & 15;
    float acc[4][4];
#pragma unroll
    for (int i = 0; i < 4; i++)
#pragma unroll
        for (int j = 0; j < 4; j++) acc[i][j] = 0.f;

    for (int k0 = 0; k0 < DS_; k0 += 32) {
#pragma unroll
        for (int i = 0; i < 2; i++) {
            int m = lr + i * 32;
            float4 a4 = *(const float4*)(Yn + (size_t)(m0 + m) * DS_ + k0 + lk4 * 4);
            As[lk4*4+0][m] = a4.x; As[lk4*4+1][m] = a4.y;
            As[lk4*4+2][m] = a4.z; As[lk4*4+3][m] = a4.w;
            float4 b4 = *(const float4*)(Wo + (size_t)(n0 + m) * DS_ + k0 + lk4 * 4);
            Bs[lk4*4+0][m] = b4.x; Bs[lk4*4+1][m] = b4.y;
            Bs[lk4*4+2][m] = b4.z; Bs[lk4*4+3][m] = b4.w;
        }
        __syncthreads();
#pragma unroll
        for (int kk = 0; kk < 32; kk++) {
            float4 a4 = *(const float4*)(&As[kk][ty * 4]);
            float4 b4 = *(const float4*)(&Bs[kk][tx * 4]);
            float a[4] = {a4.x, a4.y, a4.z, a4.w};
            float b[4] = {b4.x, b4.y, b4.z, b4.w};
#pragma unroll
            for (int i = 0; i < 4; i++)
#pragma unroll
                for (int j = 0; j < 4; j++)
                    acc[i][j] = fmaf(a[i], b[j], acc[i][j]);
        }
        __syncthreads();
    }
#pragma unroll
    for (int i = 0; i < 4; i++) {
        float4 o; o.x = acc[i][0]; o.y = acc[i][1]; o.z = acc[i][2]; o.w = acc[i][3];
        *(float4*)(Out + (size_t)(m0 + ty * 4 + i) * 1024 + n0 + tx * 4) = o;
    }
}

// ---------------------------------------------------------------------------
extern "C" void kernel_launch(void* const* d_in, const int* in_sizes, int n_in,
                              void* d_out, int out_size, void* d_ws, size_t ws_size,
                              hipStream_t stream)
{
    const float* x   = (const float*)d_in[0];
    const float* Wk  = (const float*)d_in[1];
    const float* Wv  = (const float*)d_in[2];
    const float* Wq  = (const float*)d_in[3];
    const float* Waw = (const float*)d_in[4];
    const float* Wab = (const float*)d_in[5];
    const float* lam = (const float*)d_in[6];
    const float* Wo  = (const float*)d_in[7];
    const float* nw  = (const float*)d_in[8];
    float* out = (float*)d_out;

    const size_t NTOK = (size_t)B_SZ * S_LEN;   // 16384
    float* P  = (float*)d_ws;                    // NTOK*512
    float* Q2 = P + NTOK * 512;                  // NTOK*QROW
    float* Y  = Q2 + NTOK * QROW;                // NTOK*128

    proj_gemm<<<dim3(NTOK / 64, 512 / 64), 256, 0, stream>>>(x, Wk, Wv, Wq, Waw, P);
    postproc<<<NTOK, 128, 0, stream>>>(P, Q2, Wab, lam);
    recurrence<<<B_SZ, 512, 0, stream>>>(P, Q2, Y);
    rmsnorm<<<NTOK, 128, 0, stream>>>(Y, nw);
    out_gemm<<<dim3(NTOK / 64, 1024 / 64), 256, 0, stream>>>(Y, Wo, out);
}

// Round 4
// 3776.535 us; speedup vs baseline: 1.0008x; 1.0008x over previous
//
#include <hip/hip_runtime.h>
#include <math.h>

#define S_LEN 2048
#define B_SZ 8
#define D_IN 1024
#define DS_ 128
#define INV_TEMP (1.0f/1.000001f)
#define QROW 260    // Q2 row stride: qa(128) ka1(128) g(1) pad
#define LBUF 1092   // LDS floats per step slot: 5 sections*192 + v(128) + g + pad

// Relaxed workgroup barrier: orders LDS ops (lgkmcnt) but does NOT drain
// in-flight global loads (vmcnt) the way __syncthreads() does. The prefetch
// loads issued right before this barrier stay in flight; their vmcnt wait
// lands at the consuming ds_write one full step later.
#define BAR_LDS() asm volatile("s_waitcnt lgkmcnt(0)\n\ts_barrier" ::: "memory")

// ---------------------------------------------------------------------------
// Kernel 1: fused projection GEMM  P[16384][512] = x @ [Wk|Wv|Wq|Wa]^T
// P row layout: k(0..127) v(128..255) q(256..383) r(384..511)
// ---------------------------------------------------------------------------
__global__ __launch_bounds__(256) void proj_gemm(
    const float* __restrict__ X,
    const float* __restrict__ Wk, const float* __restrict__ Wv,
    const float* __restrict__ Wq, const float* __restrict__ Wa,
    float* __restrict__ P)
{
    __shared__ __align__(16) float As[32][68];
    __shared__ __align__(16) float Bs[32][68];
    const int tid = threadIdx.x;
    const int m0 = blockIdx.x * 64;
    const int n0 = blockIdx.y * 64;
    const int lr = tid >> 3;
    const int lk4 = tid & 7;

    const float* wrows[2];
#pragma unroll
    for (int i = 0; i < 2; i++) {
        int nn = n0 + lr + i * 32;
        const float* w;
        if      (nn < 128) w = Wk + (size_t)nn * D_IN;
        else if (nn < 256) w = Wv + (size_t)(nn - 128) * D_IN;
        else if (nn < 384) w = Wq + (size_t)(nn - 256) * D_IN;
        else               w = Wa + (size_t)(nn - 384) * D_IN;
        wrows[i] = w;
    }
    const int ty = tid >> 4, tx = tid & 15;
    float acc[4][4];
#pragma unroll
    for (int i = 0; i < 4; i++)
#pragma unroll
        for (int j = 0; j < 4; j++) acc[i][j] = 0.f;

    for (int k0 = 0; k0 < D_IN; k0 += 32) {
#pragma unroll
        for (int i = 0; i < 2; i++) {
            int m = lr + i * 32;
            float4 a4 = *(const float4*)(X + (size_t)(m0 + m) * D_IN + k0 + lk4 * 4);
            As[lk4*4+0][m] = a4.x; As[lk4*4+1][m] = a4.y;
            As[lk4*4+2][m] = a4.z; As[lk4*4+3][m] = a4.w;
            float4 b4 = *(const float4*)(wrows[i] + k0 + lk4 * 4);
            Bs[lk4*4+0][m] = b4.x; Bs[lk4*4+1][m] = b4.y;
            Bs[lk4*4+2][m] = b4.z; Bs[lk4*4+3][m] = b4.w;
        }
        __syncthreads();
#pragma unroll
        for (int kk = 0; kk < 32; kk++) {
            float4 a4 = *(const float4*)(&As[kk][ty * 4]);
            float4 b4 = *(const float4*)(&Bs[kk][tx * 4]);
            float a[4] = {a4.x, a4.y, a4.z, a4.w};
            float b[4] = {b4.x, b4.y, b4.z, b4.w};
#pragma unroll
            for (int i = 0; i < 4; i++)
#pragma unroll
                for (int j = 0; j < 4; j++)
                    acc[i][j] = fmaf(a[i], b[j], acc[i][j]);
        }
        __syncthreads();
    }
#pragma unroll
    for (int i = 0; i < 4; i++) {
        float4 o; o.x = acc[i][0]; o.y = acc[i][1]; o.z = acc[i][2]; o.w = acc[i][3];
        *(float4*)(P + (size_t)(m0 + ty * 4 + i) * 512 + n0 + tx * 4) = o;
    }
}

// ---------------------------------------------------------------------------
// Kernel 2: postprocess per token. In-place on P: k<-l2norm(k), q<-l2norm(q),
// r-slot<-alpha. Side buffer Q2: qa=q*alpha, ka1=k*(1-alpha), g=sum q(1-a)k.
// ---------------------------------------------------------------------------
__global__ __launch_bounds__(128) void postproc(
    float* __restrict__ P, float* __restrict__ Q2,
    const float* __restrict__ bA, const float* __restrict__ lam)
{
    const int tok = blockIdx.x, i = threadIdx.x;
    float* row = P + (size_t)tok * 512;
    float kr = row[i], qr = row[256 + i], rr = row[384 + i];
    float ks = kr * kr, qs = qr * qr;
#pragma unroll
    for (int m = 1; m < 64; m <<= 1) { ks += __shfl_xor(ks, m); qs += __shfl_xor(qs, m); }
    __shared__ float sb[6];
    if ((i & 63) == 0) { sb[(i >> 6) * 2] = ks; sb[(i >> 6) * 2 + 1] = qs; }
    __syncthreads();
    float kinv = 1.0f / fmaxf(sqrtf(sb[0] + sb[2]), 1e-12f);
    float qinv = 1.0f / fmaxf(sqrtf(sb[1] + sb[3]), 1e-12f);
    float kn = kr * kinv, qn = qr * qinv;
    float sr = 1.0f / (1.0f + __expf(-(rr + bA[i])));
    float sl = 1.0f / (1.0f + __expf(-lam[i]));
    float la = logf(sl + 1e-8f);
    float al = __expf(8.0f * sr * la);
    row[i] = kn; row[256 + i] = qn; row[384 + i] = al;
    float* q2 = Q2 + (size_t)tok * QROW;
    q2[i] = qn * al;
    q2[128 + i] = kn * (1.0f - al);
    float gi = qn * (1.0f - al) * kn;
#pragma unroll
    for (int m = 1; m < 64; m <<= 1) gi += __shfl_xor(gi, m);
    if ((i & 63) == 0) sb[4 + (i >> 6)] = gi;
    __syncthreads();
    if (i == 0) q2[256] = sb[4] + sb[5];
}

// ---------------------------------------------------------------------------
// Kernel 3: sequential recurrence. 8 blocks x 512 threads.
// Thread (c=tid&15, vp=tid>>4) owns H[k][v], k in [c*8,c*8+8), v in [vp*4,vp*4+4).
// LDS step slot: sections k@0 q@192 qa@384 a@576 ka1@768 (16 chunks of 8,
// stride 12), v@960, g@1088. One RELAXED barrier/step (lgkmcnt only —
// global prefetch stays in flight across it); 2-deep global prefetch.
// ---------------------------------------------------------------------------
__global__ __launch_bounds__(512, 2) void recurrence(
    const float* __restrict__ P, const float* __restrict__ Q2, float* __restrict__ Y)
{
    const int b = blockIdx.x;
    const int tid = threadIdx.x;
    const int c = tid & 15;
    const int vp = tid >> 4;      // 0..31
    const int lane = tid & 63;
    const int wave = tid >> 6;    // 0..7
    const int co = c * 12;

    __shared__ __align__(16) float Pbuf[3][LBUF];
    __shared__ __align__(16) float errw[2][8];

    const float* Pb = P + (size_t)b * S_LEN * 512;
    const float* Qb = Q2 + (size_t)b * S_LEN * QROW;
    float* Yb = Y + (size_t)b * S_LEN * DS_;

    float4 H0={0,0,0,0},H1={0,0,0,0},H2={0,0,0,0},H3={0,0,0,0},
           H4={0,0,0,0},H5={0,0,0,0},H6={0,0,0,0},H7={0,0,0,0};

    const bool isS = tid < 385;
    int spos = 0; const float* src = nullptr; int sstr = 0;
    if (tid < 256) {
        int i = tid * 2, s = i >> 7, idx = i & 127, cp = (idx >> 3) * 12 + (idx & 7);
        spos = (s == 0) ? cp : (s == 1) ? (960 + idx) : (s == 2) ? (192 + cp) : (576 + cp);
        src = Pb + i; sstr = 512;
    } else if (tid < 385) {
        int i2 = (tid - 256) * 2, s = i2 >> 7, idx = i2 & 127, cp = (idx >> 3) * 12 + (idx & 7);
        spos = (tid == 384) ? 1088 : ((s == 0) ? (384 + cp) : (768 + cp));
        src = Qb + i2; sstr = QROW;
    }

    float2 r0 = {0.f, 0.f}, r1 = {0.f, 0.f};
    if (isS) { r0 = *(const float2*)(src); r1 = *(const float2*)(src + sstr); }
    if (isS) *(float2*)(&Pbuf[0][spos]) = r0;
    __syncthreads();

#define RED16(v4) { _Pragma("unroll") for (int m_ = 1; m_ < 16; m_ <<= 1) { \
    v4.x += __shfl_xor(v4.x, m_); v4.y += __shfl_xor(v4.y, m_); \
    v4.z += __shfl_xor(v4.z, m_); v4.w += __shfl_xor(v4.w, m_); } }

#define DOTJ(qs, ks, zs, Hj) { \
    pr.x = fmaf(qs, Hj.x, pr.x); pr.y = fmaf(qs, Hj.y, pr.y); \
    pr.z = fmaf(qs, Hj.z, pr.z); pr.w = fmaf(qs, Hj.w, pr.w); \
    kp.x = fmaf(ks, Hj.x, kp.x); kp.y = fmaf(ks, Hj.y, kp.y); \
    kp.z = fmaf(ks, Hj.z, kp.z); kp.w = fmaf(ks, Hj.w, kp.w); \
    ya.x = fmaf(zs, Hj.x, ya.x); ya.y = fmaf(zs, Hj.y, ya.y); \
    ya.z = fmaf(zs, Hj.z, ya.z); ya.w = fmaf(zs, Hj.w, ya.w); }

#define UPDJ(as_, ws_, Hj) { \
    Hj.x = fmaf(as_, Hj.x, ws_ * sd.x); Hj.y = fmaf(as_, Hj.y, ws_ * sd.y); \
    Hj.z = fmaf(as_, Hj.z, ws_ * sd.z); Hj.w = fmaf(as_, Hj.w, ws_ * sd.w); }

#define STEP(T, PAR, RS_, RL_) { \
    float* cb = &Pbuf[(T) % 3][0]; \
    const float4 k0 = *(const float4*)(cb + co); \
    const float4 k1 = *(const float4*)(cb + co + 4); \
    const float4 q0 = *(const float4*)(cb + 192 + co); \
    const float4 q1 = *(const float4*)(cb + 192 + co + 4); \
    const float4 z0 = *(const float4*)(cb + 384 + co); \
    const float4 z1 = *(const float4*)(cb + 384 + co + 4); \
    const float4 vt = *(const float4*)(cb + 960 + vp * 4); \
    const float g = cb[1088]; \
    float4 pr = {0,0,0,0}, kp = {0,0,0,0}, ya = {0,0,0,0}; \
    DOTJ(q0.x, k0.x, z0.x, H0) DOTJ(q0.y, k0.y, z0.y, H1) \
    DOTJ(q0.z, k0.z, z0.z, H2) DOTJ(q0.w, k0.w, z0.w, H3) \
    DOTJ(q1.x, k1.x, z1.x, H4) DOTJ(q1.y, k1.y, z1.y, H5) \
    DOTJ(q1.z, k1.z, z1.z, H6) DOTJ(q1.w, k1.w, z1.w, H7) \
    RED16(pr) RED16(kp) RED16(ya) \
    float4 d4; d4.x = vt.x - kp.x; d4.y = vt.y - kp.y; \
    d4.z = vt.z - kp.z; d4.w = vt.w - kp.w; \
    float ex = vt.x - pr.x, ey = vt.y - pr.y, ez = vt.z - pr.z, ew = vt.w - pr.w; \
    float ep = fmaf(ex, ex, fmaf(ey, ey, fmaf(ez, ez, ew * ew))); \
    ep += __shfl_xor(ep, 16); ep += __shfl_xor(ep, 32); \
    if (lane == 0) errw[PAR][wave] = ep; \
    if ((T) + 1 < S_LEN && isS) *(float2*)(&Pbuf[((T) + 1) % 3][spos]) = RS_; \
    if ((T) + 2 < S_LEN && isS) RL_ = *(const float2*)(src + (size_t)((T) + 2) * sstr); \
    const float4 a0 = *(const float4*)(cb + 576 + co); \
    const float4 a1 = *(const float4*)(cb + 576 + co + 4); \
    const float4 w0 = *(const float4*)(cb + 768 + co); \
    const float4 w1 = *(const float4*)(cb + 768 + co + 4); \
    BAR_LDS(); \
    const float4 ea = *(const float4*)(&errw[PAR][0]); \
    const float4 eb = *(const float4*)(&errw[PAR][4]); \
    float err = ((ea.x + ea.y) + (ea.z + ea.w)) + ((eb.x + eb.y) + (eb.z + eb.w)); \
    float sur = 1.0f / (1.0f + __expf(-err * INV_TEMP)); \
    float4 sd; sd.x = sur * d4.x; sd.y = sur * d4.y; \
    sd.z = sur * d4.z; sd.w = sur * d4.w; \
    if (c == 0) { \
        float sg = sur * g; float4 y4; \
        y4.x = fmaf(sg, d4.x, ya.x); y4.y = fmaf(sg, d4.y, ya.y); \
        y4.z = fmaf(sg, d4.z, ya.z); y4.w = fmaf(sg, d4.w, ya.w); \
        *(float4*)(Yb + (size_t)(T) * DS_ + vp * 4) = y4; } \
    UPDJ(a0.x, w0.x, H0) UPDJ(a0.y, w0.y, H1) \
    UPDJ(a0.z, w0.z, H2) UPDJ(a0.w, w0.w, H3) \
    UPDJ(a1.x, w1.x, H4) UPDJ(a1.y, w1.y, H5) \
    UPDJ(a1.z, w1.z, H6) UPDJ(a1.w, w1.w, H7) \
}

    for (int t = 0; t < S_LEN; t += 2) {
        STEP(t,     0, r1, r0)
        STEP(t + 1, 1, r0, r1)
    }
#undef RED16
#undef DOTJ
#undef UPDJ
#undef STEP
}

// ---------------------------------------------------------------------------
// Kernel 4: RMSNorm over DS per token (in-place on Y)
// ---------------------------------------------------------------------------
__global__ __launch_bounds__(128) void rmsnorm(
    float* __restrict__ Y, const float* __restrict__ nw)
{
    const int tok = blockIdx.x, i = threadIdx.x;
    float y = Y[(size_t)tok * DS_ + i];
    float s = y * y;
#pragma unroll
    for (int m = 1; m < 64; m <<= 1) s += __shfl_xor(s, m);
    __shared__ float sb[2];
    if ((i & 63) == 0) sb[i >> 6] = s;
    __syncthreads();
    float ms = (sb[0] + sb[1]) * (1.0f / 128.0f);
    Y[(size_t)tok * DS_ + i] = y * rsqrtf(ms + 1e-6f) * nw[i];
}

// ---------------------------------------------------------------------------
// Kernel 5: output GEMM  Out[16384][1024] = Yn[16384][128] @ Wo[1024][128]^T
// ---------------------------------------------------------------------------
__global__ __launch_bounds__(256) void out_gemm(
    const float* __restrict__ Yn, const float* __restrict__ Wo, float* __restrict__ Out)
{
    __shared__ __align__(16) float As[32][68];
    __shared__ __align__(16) float Bs[32][68];
    const int tid = threadIdx.x;
    const int m0 = blockIdx.x * 64;
    const int n0 = blockIdx.y * 64;
    const int lr = tid >> 3;
    const int lk4 = tid & 7;
    const int ty = tid >> 4, tx = tid & 15;
    float acc[4][4];
#pragma unroll
    for (int i = 0; i < 4; i++)
#pragma unroll
        for (int j = 0; j < 4; j++) acc[i][j] = 0.f;

    for (int k0 = 0; k0 < DS_; k0 += 32) {
#pragma unroll
        for (int i = 0; i < 2; i++) {
            int m = lr + i * 32;
            float4 a4 = *(const float4*)(Yn + (size_t)(m0 + m) * DS_ + k0 + lk4 * 4);
            As[lk4*4+0][m] = a4.x; As[lk4*4+1][m] = a4.y;
            As[lk4*4+2][m] = a4.z; As[lk4*4+3][m] = a4.w;
            float4 b4 = *(const float4*)(Wo + (size_t)(n0 + m) * DS_ + k0 + lk4 * 4);
            Bs[lk4*4+0][m] = b4.x; Bs[lk4*4+1][m] = b4.y;
            Bs[lk4*4+2][m] = b4.z; Bs[lk4*4+3][m] = b4.w;
        }
        __syncthreads();
#pragma unroll
        for (int kk = 0; kk < 32; kk++) {
            float4 a4 = *(const float4*)(&As[kk][ty * 4]);
            float4 b4 = *(const float4*)(&Bs[kk][tx * 4]);
            float a[4] = {a4.x, a4.y, a4.z, a4.w};
            float b[4] = {b4.x, b4.y, b4.z, b4.w};
#pragma unroll
            for (int i = 0; i < 4; i++)
#pragma unroll
                for (int j = 0; j < 4; j++)
                    acc[i][j] = fmaf(a[i], b[j], acc[i][j]);
        }
        __syncthreads();
    }
#pragma unroll
    for (int i = 0; i < 4; i++) {
        float4 o; o.x = acc[i][0]; o.y = acc[i][1]; o.z = acc[i][2]; o.w = acc[i][3];
        *(float4*)(Out + (size_t)(m0 + ty * 4 + i) * 1024 + n0 + tx * 4) = o;
    }
}

// ---------------------------------------------------------------------------
extern "C" void kernel_launch(void* const* d_in, const int* in_sizes, int n_in,
                              void* d_out, int out_size, void* d_ws, size_t ws_size,
                              hipStream_t stream)
{
    const float* x   = (const float*)d_in[0];
    const float* Wk  = (const float*)d_in[1];
    const float* Wv  = (const float*)d_in[2];
    const float* Wq  = (const float*)d_in[3];
    const float* Waw = (const float*)d_in[4];
    const float* Wab = (const float*)d_in[5];
    const float* lam = (const float*)d_in[6];
    const float* Wo  = (const float*)d_in[7];
    const float* nw  = (const float*)d_in[8];
    float* out = (float*)d_out;

    const size_t NTOK = (size_t)B_SZ * S_LEN;   // 16384
    float* P  = (float*)d_ws;                    // NTOK*512
    float* Q2 = P + NTOK * 512;                  // NTOK*QROW
    float* Y  = Q2 + NTOK * QROW;                // NTOK*128

    proj_gemm<<<dim3(NTOK / 64, 512 / 64), 256, 0, stream>>>(x, Wk, Wv, Wq, Waw, P);
    postproc<<<NTOK, 128, 0, stream>>>(P, Q2, Wab, lam);
    recurrence<<<B_SZ, 512, 0, stream>>>(P, Q2, Y);
    rmsnorm<<<NTOK, 128, 0, stream>>>(Y, nw);
    out_gemm<<<dim3(NTOK / 64, 1024 / 64), 256, 0, stream>>>(Y, Wo, out);
}

// Round 5
// 2743.315 us; speedup vs baseline: 1.3777x; 1.3766x over previous
//
#include <hip/hip_runtime.h>
#include <math.h>

#define S_LEN 2048
#define B_SZ 8
#define D_IN 1024
#define DS_ 128
#define INV_TEMP (1.0f/1.000001f)
#define LBUF 712    // LDS floats per step slot: k@0 q@192 a@384 (16 chunks of 8, stride 12), v@576, g@704

// Relaxed workgroup barrier: orders LDS ops only (no vmcnt drain).
#define BAR_LDS() asm volatile("s_waitcnt lgkmcnt(0)\n\ts_barrier" ::: "memory")

// DPP row-butterfly sum across the 16-lane row (lanes sharing tid>>4).
// row_ror:N is VALU-pipe cross-lane — no LDS traffic (vs __shfl_xor = ds_swizzle).
#define DPPADD(x, ctrl) { int t_ = __builtin_amdgcn_update_dpp( \
    0, __float_as_int(x), ctrl, 0xF, 0xF, false); x += __int_as_float(t_); }
#define ROWSUM(x) { DPPADD(x, 0x128) DPPADD(x, 0x124) DPPADD(x, 0x122) DPPADD(x, 0x121) }
#define ROWSUM4(v4) { ROWSUM(v4.x) ROWSUM(v4.y) ROWSUM(v4.z) ROWSUM(v4.w) }

// ---------------------------------------------------------------------------
// Kernel 1: fused projection GEMM  P[16384][512] = x @ [Wk|Wv|Wq|Wa]^T
// P row layout: k(0..127) v(128..255) q(256..383) r(384..511)
// ---------------------------------------------------------------------------
__global__ __launch_bounds__(256) void proj_gemm(
    const float* __restrict__ X,
    const float* __restrict__ Wk, const float* __restrict__ Wv,
    const float* __restrict__ Wq, const float* __restrict__ Wa,
    float* __restrict__ P)
{
    __shared__ __align__(16) float As[32][68];
    __shared__ __align__(16) float Bs[32][68];
    const int tid = threadIdx.x;
    const int m0 = blockIdx.x * 64;
    const int n0 = blockIdx.y * 64;
    const int lr = tid >> 3;
    const int lk4 = tid & 7;

    const float* wrows[2];
#pragma unroll
    for (int i = 0; i < 2; i++) {
        int nn = n0 + lr + i * 32;
        const float* w;
        if      (nn < 128) w = Wk + (size_t)nn * D_IN;
        else if (nn < 256) w = Wv + (size_t)(nn - 128) * D_IN;
        else if (nn < 384) w = Wq + (size_t)(nn - 256) * D_IN;
        else               w = Wa + (size_t)(nn - 384) * D_IN;
        wrows[i] = w;
    }
    const int ty = tid >> 4, tx = tid & 15;
    float acc[4][4];
#pragma unroll
    for (int i = 0; i < 4; i++)
#pragma unroll
        for (int j = 0; j < 4; j++) acc[i][j] = 0.f;

    for (int k0 = 0; k0 < D_IN; k0 += 32) {
#pragma unroll
        for (int i = 0; i < 2; i++) {
            int m = lr + i * 32;
            float4 a4 = *(const float4*)(X + (size_t)(m0 + m) * D_IN + k0 + lk4 * 4);
            As[lk4*4+0][m] = a4.x; As[lk4*4+1][m] = a4.y;
            As[lk4*4+2][m] = a4.z; As[lk4*4+3][m] = a4.w;
            float4 b4 = *(const float4*)(wrows[i] + k0 + lk4 * 4);
            Bs[lk4*4+0][m] = b4.x; Bs[lk4*4+1][m] = b4.y;
            Bs[lk4*4+2][m] = b4.z; Bs[lk4*4+3][m] = b4.w;
        }
        __syncthreads();
#pragma unroll
        for (int kk = 0; kk < 32; kk++) {
            float4 a4 = *(const float4*)(&As[kk][ty * 4]);
            float4 b4 = *(const float4*)(&Bs[kk][tx * 4]);
            float a[4] = {a4.x, a4.y, a4.z, a4.w};
            float b[4] = {b4.x, b4.y, b4.z, b4.w};
#pragma unroll
            for (int i = 0; i < 4; i++)
#pragma unroll
                for (int j = 0; j < 4; j++)
                    acc[i][j] = fmaf(a[i], b[j], acc[i][j]);
        }
        __syncthreads();
    }
#pragma unroll
    for (int i = 0; i < 4; i++) {
        float4 o; o.x = acc[i][0]; o.y = acc[i][1]; o.z = acc[i][2]; o.w = acc[i][3];
        *(float4*)(P + (size_t)(m0 + ty * 4 + i) * 512 + n0 + tx * 4) = o;
    }
}

// ---------------------------------------------------------------------------
// Kernel 2: postprocess per token. In-place on P: k<-l2norm(k), q<-l2norm(q),
// r-slot<-alpha. G[tok] = sum_k q_k*(1-alpha_k)*k_k.
// ---------------------------------------------------------------------------
__global__ __launch_bounds__(128) void postproc(
    float* __restrict__ P, float* __restrict__ G,
    const float* __restrict__ bA, const float* __restrict__ lam)
{
    const int tok = blockIdx.x, i = threadIdx.x;
    float* row = P + (size_t)tok * 512;
    float kr = row[i], qr = row[256 + i], rr = row[384 + i];
    float ks = kr * kr, qs = qr * qr;
#pragma unroll
    for (int m = 1; m < 64; m <<= 1) { ks += __shfl_xor(ks, m); qs += __shfl_xor(qs, m); }
    __shared__ float sb[6];
    if ((i & 63) == 0) { sb[(i >> 6) * 2] = ks; sb[(i >> 6) * 2 + 1] = qs; }
    __syncthreads();
    float kinv = 1.0f / fmaxf(sqrtf(sb[0] + sb[2]), 1e-12f);
    float qinv = 1.0f / fmaxf(sqrtf(sb[1] + sb[3]), 1e-12f);
    float kn = kr * kinv, qn = qr * qinv;
    float sr = 1.0f / (1.0f + __expf(-(rr + bA[i])));
    float sl = 1.0f / (1.0f + __expf(-lam[i]));
    float la = logf(sl + 1e-8f);
    float al = __expf(8.0f * sr * la);
    row[i] = kn; row[256 + i] = qn; row[384 + i] = al;
    float gi = qn * (1.0f - al) * kn;
#pragma unroll
    for (int m = 1; m < 64; m <<= 1) gi += __shfl_xor(gi, m);
    if ((i & 63) == 0) sb[4 + (i >> 6)] = gi;
    __syncthreads();
    if (i == 0) G[tok] = sb[4] + sb[5];
}

// ---------------------------------------------------------------------------
// Kernel 3: sequential recurrence. 8 blocks x 512 threads.
// Thread (c=tid&15, vp=tid>>4) owns H[k][v], k in [c*8,c*8+8), v in [vp*4,vp*4+4).
// Per step LDS reads per thread: k,q,a 2 b128 each + vt 1 b128 + g b32.
// z=q*a and w=k*(1-a) computed in-registers. k-reduction via DPP row_ror
// butterfly (VALU pipe) — no ds_swizzle. One relaxed barrier/step; 2-deep
// register prefetch of the next tokens' P row + g.
// ---------------------------------------------------------------------------
__global__ __launch_bounds__(512, 2) void recurrence(
    const float* __restrict__ P, const float* __restrict__ G, float* __restrict__ Y)
{
    const int b = blockIdx.x;
    const int tid = threadIdx.x;
    const int c = tid & 15;
    const int vp = tid >> 4;      // 0..31
    const int lane = tid & 63;
    const int wave = tid >> 6;    // 0..7
    const int co = c * 12;

    __shared__ __align__(16) float Pbuf[3][LBUF];
    __shared__ __align__(16) float errw[2][8];

    const float* Pb = P + (size_t)b * S_LEN * 512;
    const float* Gb = G + (size_t)b * S_LEN;
    float* Yb = Y + (size_t)b * S_LEN * DS_;

    float4 H0={0,0,0,0},H1={0,0,0,0},H2={0,0,0,0},H3={0,0,0,0},
           H4={0,0,0,0},H5={0,0,0,0},H6={0,0,0,0},H7={0,0,0,0};

    const bool isP = tid < 256;
    const bool isG = (tid == 256);
    int spos = 0;
    if (isP) {
        int i = tid * 2, s = i >> 7, idx = i & 127, cp = (idx >> 3) * 12 + (idx & 7);
        spos = (s == 0) ? cp : (s == 1) ? (576 + idx) : (s == 2) ? (192 + cp) : (384 + cp);
    }

    float2 rp0 = {0.f, 0.f}, rp1 = {0.f, 0.f};
    float rg0 = 0.f, rg1 = 0.f;
    if (isP) { rp0 = *(const float2*)(Pb + tid * 2); rp1 = *(const float2*)(Pb + 512 + tid * 2); }
    if (isG) { rg0 = Gb[0]; rg1 = Gb[1]; }
    if (isP) *(float2*)(&Pbuf[0][spos]) = rp0;
    if (isG) Pbuf[0][704] = rg0;
    __syncthreads();

#define DOTJ(qs, ks, zs, Hj) { \
    pr.x = fmaf(qs, Hj.x, pr.x); pr.y = fmaf(qs, Hj.y, pr.y); \
    pr.z = fmaf(qs, Hj.z, pr.z); pr.w = fmaf(qs, Hj.w, pr.w); \
    kp.x = fmaf(ks, Hj.x, kp.x); kp.y = fmaf(ks, Hj.y, kp.y); \
    kp.z = fmaf(ks, Hj.z, kp.z); kp.w = fmaf(ks, Hj.w, kp.w); \
    ya.x = fmaf(zs, Hj.x, ya.x); ya.y = fmaf(zs, Hj.y, ya.y); \
    ya.z = fmaf(zs, Hj.z, ya.z); ya.w = fmaf(zs, Hj.w, ya.w); }

#define UPDJ(as_, ws_, Hj) { \
    Hj.x = fmaf(as_, Hj.x, ws_ * sd.x); Hj.y = fmaf(as_, Hj.y, ws_ * sd.y); \
    Hj.z = fmaf(as_, Hj.z, ws_ * sd.z); Hj.w = fmaf(as_, Hj.w, ws_ * sd.w); }

#define STEP(T, PAR, RPS, RGS, RPL, RGL) { \
    float* cb = &Pbuf[(T) % 3][0]; \
    const float4 k0 = *(const float4*)(cb + co); \
    const float4 k1 = *(const float4*)(cb + co + 4); \
    const float4 q0 = *(const float4*)(cb + 192 + co); \
    const float4 q1 = *(const float4*)(cb + 192 + co + 4); \
    const float4 a0 = *(const float4*)(cb + 384 + co); \
    const float4 a1 = *(const float4*)(cb + 384 + co + 4); \
    const float4 vt = *(const float4*)(cb + 576 + vp * 4); \
    const float g = cb[704]; \
    float4 z0, z1, w0, w1; \
    z0.x = q0.x * a0.x; z0.y = q0.y * a0.y; z0.z = q0.z * a0.z; z0.w = q0.w * a0.w; \
    z1.x = q1.x * a1.x; z1.y = q1.y * a1.y; z1.z = q1.z * a1.z; z1.w = q1.w * a1.w; \
    w0.x = fmaf(-k0.x, a0.x, k0.x); w0.y = fmaf(-k0.y, a0.y, k0.y); \
    w0.z = fmaf(-k0.z, a0.z, k0.z); w0.w = fmaf(-k0.w, a0.w, k0.w); \
    w1.x = fmaf(-k1.x, a1.x, k1.x); w1.y = fmaf(-k1.y, a1.y, k1.y); \
    w1.z = fmaf(-k1.z, a1.z, k1.z); w1.w = fmaf(-k1.w, a1.w, k1.w); \
    float4 pr = {0,0,0,0}, kp = {0,0,0,0}, ya = {0,0,0,0}; \
    DOTJ(q0.x, k0.x, z0.x, H0) DOTJ(q0.y, k0.y, z0.y, H1) \
    DOTJ(q0.z, k0.z, z0.z, H2) DOTJ(q0.w, k0.w, z0.w, H3) \
    DOTJ(q1.x, k1.x, z1.x, H4) DOTJ(q1.y, k1.y, z1.y, H5) \
    DOTJ(q1.z, k1.z, z1.z, H6) DOTJ(q1.w, k1.w, z1.w, H7) \
    ROWSUM4(pr) ROWSUM4(kp) ROWSUM4(ya) \
    float4 d4; d4.x = vt.x - kp.x; d4.y = vt.y - kp.y; \
    d4.z = vt.z - kp.z; d4.w = vt.w - kp.w; \
    float ex = vt.x - pr.x, ey = vt.y - pr.y, ez = vt.z - pr.z, ew = vt.w - pr.w; \
    float ep = fmaf(ex, ex, fmaf(ey, ey, fmaf(ez, ez, ew * ew))); \
    ep += __shfl_xor(ep, 16); ep += __shfl_xor(ep, 32); \
    if (lane == 0) errw[PAR][wave] = ep; \
    if ((T) + 1 < S_LEN) { \
        if (isP) *(float2*)(&Pbuf[((T) + 1) % 3][spos]) = RPS; \
        if (isG) Pbuf[((T) + 1) % 3][704] = RGS; } \
    if ((T) + 2 < S_LEN) { \
        if (isP) RPL = *(const float2*)(Pb + (size_t)((T) + 2) * 512 + tid * 2); \
        if (isG) RGL = Gb[(T) + 2]; } \
    BAR_LDS(); \
    const float4 ea = *(const float4*)(&errw[PAR][0]); \
    const float4 eb = *(const float4*)(&errw[PAR][4]); \
    float err = ((ea.x + ea.y) + (ea.z + ea.w)) + ((eb.x + eb.y) + (eb.z + eb.w)); \
    float sur = 1.0f / (1.0f + __expf(-err * INV_TEMP)); \
    float4 sd; sd.x = sur * d4.x; sd.y = sur * d4.y; \
    sd.z = sur * d4.z; sd.w = sur * d4.w; \
    if (c == 0) { \
        float sg = sur * g; float4 y4; \
        y4.x = fmaf(sg, d4.x, ya.x); y4.y = fmaf(sg, d4.y, ya.y); \
        y4.z = fmaf(sg, d4.z, ya.z); y4.w = fmaf(sg, d4.w, ya.w); \
        *(float4*)(Yb + (size_t)(T) * DS_ + vp * 4) = y4; } \
    UPDJ(a0.x, w0.x, H0) UPDJ(a0.y, w0.y, H1) \
    UPDJ(a0.z, w0.z, H2) UPDJ(a0.w, w0.w, H3) \
    UPDJ(a1.x, w1.x, H4) UPDJ(a1.y, w1.y, H5) \
    UPDJ(a1.z, w1.z, H6) UPDJ(a1.w, w1.w, H7) \
}

    for (int t = 0; t < S_LEN; t += 2) {
        STEP(t,     0, rp1, rg1, rp0, rg0)
        STEP(t + 1, 1, rp0, rg0, rp1, rg1)
    }
#undef DOTJ
#undef UPDJ
#undef STEP
}

// ---------------------------------------------------------------------------
// Kernel 4: RMSNorm over DS per token (in-place on Y)
// ---------------------------------------------------------------------------
__global__ __launch_bounds__(128) void rmsnorm(
    float* __restrict__ Y, const float* __restrict__ nw)
{
    const int tok = blockIdx.x, i = threadIdx.x;
    float y = Y[(size_t)tok * DS_ + i];
    float s = y * y;
#pragma unroll
    for (int m = 1; m < 64; m <<= 1) s += __shfl_xor(s, m);
    __shared__ float sb[2];
    if ((i & 63) == 0) sb[i >> 6] = s;
    __syncthreads();
    float ms = (sb[0] + sb[1]) * (1.0f / 128.0f);
    Y[(size_t)tok * DS_ + i] = y * rsqrtf(ms + 1e-6f) * nw[i];
}

// ---------------------------------------------------------------------------
// Kernel 5: output GEMM  Out[16384][1024] = Yn[16384][128] @ Wo[1024][128]^T
// ---------------------------------------------------------------------------
__global__ __launch_bounds__(256) void out_gemm(
    const float* __restrict__ Yn, const float* __restrict__ Wo, float* __restrict__ Out)
{
    __shared__ __align__(16) float As[32][68];
    __shared__ __align__(16) float Bs[32][68];
    const int tid = threadIdx.x;
    const int m0 = blockIdx.x * 64;
    const int n0 = blockIdx.y * 64;
    const int lr = tid >> 3;
    const int lk4 = tid & 7;
    const int ty = tid >> 4, tx = tid & 15;
    float acc[4][4];
#pragma unroll
    for (int i = 0; i < 4; i++)
#pragma unroll
        for (int j = 0; j < 4; j++) acc[i][j] = 0.f;

    for (int k0 = 0; k0 < DS_; k0 += 32) {
#pragma unroll
        for (int i = 0; i < 2; i++) {
            int m = lr + i * 32;
            float4 a4 = *(const float4*)(Yn + (size_t)(m0 + m) * DS_ + k0 + lk4 * 4);
            As[lk4*4+0][m] = a4.x; As[lk4*4+1][m] = a4.y;
            As[lk4*4+2][m] = a4.z; As[lk4*4+3][m] = a4.w;
            float4 b4 = *(const float4*)(Wo + (size_t)(n0 + m) * DS_ + k0 + lk4 * 4);
            Bs[lk4*4+0][m] = b4.x; Bs[lk4*4+1][m] = b4.y;
            Bs[lk4*4+2][m] = b4.z; Bs[lk4*4+3][m] = b4.w;
        }
        __syncthreads();
#pragma unroll
        for (int kk = 0; kk < 32; kk++) {
            float4 a4 = *(const float4*)(&As[kk][ty * 4]);
            float4 b4 = *(const float4*)(&Bs[kk][tx * 4]);
            float a[4] = {a4.x, a4.y, a4.z, a4.w};
            float b[4] = {b4.x, b4.y, b4.z, b4.w};
#pragma unroll
            for (int i = 0; i < 4; i++)
#pragma unroll
                for (int j = 0; j < 4; j++)
                    acc[i][j] = fmaf(a[i], b[j], acc[i][j]);
        }
        __syncthreads();
    }
#pragma unroll
    for (int i = 0; i < 4; i++) {
        float4 o; o.x = acc[i][0]; o.y = acc[i][1]; o.z = acc[i][2]; o.w = acc[i][3];
        *(float4*)(Out + (size_t)(m0 + ty * 4 + i) * 1024 + n0 + tx * 4) = o;
    }
}

// ---------------------------------------------------------------------------
extern "C" void kernel_launch(void* const* d_in, const int* in_sizes, int n_in,
                              void* d_out, int out_size, void* d_ws, size_t ws_size,
                              hipStream_t stream)
{
    const float* x   = (const float*)d_in[0];
    const float* Wk  = (const float*)d_in[1];
    const float* Wv  = (const float*)d_in[2];
    const float* Wq  = (const float*)d_in[3];
    const float* Waw = (const float*)d_in[4];
    const float* Wab = (const float*)d_in[5];
    const float* lam = (const float*)d_in[6];
    const float* Wo  = (const float*)d_in[7];
    const float* nw  = (const float*)d_in[8];
    float* out = (float*)d_out;

    const size_t NTOK = (size_t)B_SZ * S_LEN;   // 16384
    float* P  = (float*)d_ws;                    // NTOK*512
    float* G  = P + NTOK * 512;                  // NTOK
    float* Y  = G + NTOK;                        // NTOK*128

    proj_gemm<<<dim3(NTOK / 64, 512 / 64), 256, 0, stream>>>(x, Wk, Wv, Wq, Waw, P);
    postproc<<<NTOK, 128, 0, stream>>>(P, G, Wab, lam);
    recurrence<<<B_SZ, 512, 0, stream>>>(P, G, Y);
    rmsnorm<<<NTOK, 128, 0, stream>>>(Y, nw);
    out_gemm<<<dim3(NTOK / 64, 1024 / 64), 256, 0, stream>>>(Y, Wo, out);
}